// Round 17
// baseline (110.770 us; speedup 1.0000x reference)
//
#include <hip/hip_runtime.h>
#include <stdint.h>

#define DD 4096
#define NPAIR 4096
#define NQUERY 4096

// padded LDS slot: +2 floats per 32-float block; keeps float2 alignment,
// <=2-way conflicts on all pass access patterns (r12-verified: conflicts==0).
#define SLOT2(i) ((i) + ((((i) >> 5)) << 1))

// in-register 16-point DFT: z[n] -> z[k], natural order both sides.
template <int INV>
static __device__ __forceinline__ void fft16(float* zr, float* zi) {
    const float K1 = 0.92387953251128674f;   // cos(pi/8)
    const float S1 = 0.38268343236508978f;   // sin(pi/8)
    const float C2 = 0.70710678118654752f;
    float gr[16], gi[16];                    // g[k1*4 + n2]
    #pragma unroll
    for (int n2 = 0; n2 < 4; ++n2) {
        const float x0r = zr[n2],      x0i = zi[n2];
        const float x1r = zr[4 + n2],  x1i = zi[4 + n2];
        const float x2r = zr[8 + n2],  x2i = zi[8 + n2];
        const float x3r = zr[12 + n2], x3i = zi[12 + n2];
        const float s02r = x0r + x2r, s02i = x0i + x2i;
        const float d02r = x0r - x2r, d02i = x0i - x2i;
        const float s13r = x1r + x3r, s13i = x1i + x3i;
        const float d13r = x1r - x3r, d13i = x1i - x3i;
        gr[0 * 4 + n2] = s02r + s13r; gi[0 * 4 + n2] = s02i + s13i;
        gr[2 * 4 + n2] = s02r - s13r; gi[2 * 4 + n2] = s02i - s13i;
        if (!INV) {
            gr[1 * 4 + n2] = d02r + d13i; gi[1 * 4 + n2] = d02i - d13r;
            gr[3 * 4 + n2] = d02r - d13i; gi[3 * 4 + n2] = d02i + d13r;
        } else {
            gr[1 * 4 + n2] = d02r - d13i; gi[1 * 4 + n2] = d02i + d13r;
            gr[3 * 4 + n2] = d02r + d13i; gi[3 * 4 + n2] = d02i - d13r;
        }
    }
#define TW16(K, N, WR, WI) do {                                              \
        const float wr_ = (WR), wi_ = INV ? -(WI) : (WI);                    \
        const float xr_ = gr[(K) * 4 + (N)], xi_ = gi[(K) * 4 + (N)];        \
        gr[(K) * 4 + (N)] = xr_ * wr_ - xi_ * wi_;                           \
        gi[(K) * 4 + (N)] = xr_ * wi_ + xi_ * wr_; } while (0)
    TW16(1, 1, K1, -S1);  TW16(1, 2, C2, -C2);   TW16(1, 3, S1, -K1);
    TW16(2, 1, C2, -C2);  TW16(2, 2, 0.f, -1.f); TW16(2, 3, -C2, -C2);
    TW16(3, 1, S1, -K1);  TW16(3, 2, -C2, -C2);  TW16(3, 3, -K1, S1);
#undef TW16
    #pragma unroll
    for (int k1 = 0; k1 < 4; ++k1) {
        const float x0r = gr[k1 * 4 + 0], x0i = gi[k1 * 4 + 0];
        const float x1r = gr[k1 * 4 + 1], x1i = gi[k1 * 4 + 1];
        const float x2r = gr[k1 * 4 + 2], x2i = gi[k1 * 4 + 2];
        const float x3r = gr[k1 * 4 + 3], x3i = gi[k1 * 4 + 3];
        const float s02r = x0r + x2r, s02i = x0i + x2i;
        const float d02r = x0r - x2r, d02i = x0i - x2i;
        const float s13r = x1r + x3r, s13i = x1i + x3i;
        const float d13r = x1r - x3r, d13i = x1i - x3i;
        zr[k1]      = s02r + s13r; zi[k1]      = s02i + s13i;
        zr[k1 + 8]  = s02r - s13r; zi[k1 + 8]  = s02i - s13i;
        if (!INV) {
            zr[k1 + 4]  = d02r + d13i; zi[k1 + 4]  = d02i - d13r;
            zr[k1 + 12] = d02r - d13i; zi[k1 + 12] = d02i + d13r;
        } else {
            zr[k1 + 4]  = d02r - d13i; zi[k1 + 4]  = d02i + d13r;
            zr[k1 + 12] = d02r + d13i; zi[k1 + 12] = d02i - d13r;
        }
    }
}

// z[k] *= base^k for k=1..15 (chained powers, 2 live regs, no LDS)
static __device__ __forceinline__ void twiddle_chain(float* zr, float* zi,
                                                     float br, float bi) {
    float cr = br, ci = bi;
    #pragma unroll
    for (int k = 1; k < 16; ++k) {
        const float xr = zr[k], xi = zi[k];
        zr[k] = xr * cr - xi * ci;
        zi[k] = xr * ci + xi * cr;
        if (k < 15) {
            const float nr = cr * br - ci * bi;
            const float ni = cr * bi + ci * br;
            cr = nr; ci = ni;
        }
    }
}

// 4096-pt FFT; pass-1 input from caller regs z (column n: z[n] = x[n*256+tid]).
// WB3=1: natural-order writeback to xr/xi + trailing barrier.
// WB3=0: result stays in regs, f = ob + j2*256, ob=(tid>>4)+(tid&15)*16;
//        no trailing barrier (caller must sync before reusing xr/xi).
template <int INV, int WB3>
static __device__ void fft4096z(float* xr, float* xi, float* zr, float* zi,
                                float b1r, float b1i, float b2r, float b2i,
                                int tid) {
    fft16<INV>(zr, zi);
    twiddle_chain(zr, zi, b1r, b1i);
    #pragma unroll
    for (int k = 0; k < 16; ++k) {
        const int a = SLOT2(k * 256 + tid);
        xr[a] = zr[k]; xi[a] = zi[k];
    }
    __syncthreads();
    const int base2 = (tid >> 4) * 256 + (tid & 15);
    #pragma unroll
    for (int m = 0; m < 16; ++m) {
        const int a = SLOT2(base2 + m * 16);
        zr[m] = xr[a]; zi[m] = xi[a];
    }
    fft16<INV>(zr, zi);
    twiddle_chain(zr, zi, b2r, b2i);
    #pragma unroll
    for (int j = 0; j < 16; ++j) {
        const int a = SLOT2(base2 + j * 16);
        xr[a] = zr[j]; xi[a] = zi[j];
    }
    __syncthreads();
    const int base3 = (tid >> 4) * 256 + (tid & 15) * 16;
    #pragma unroll
    for (int m = 0; m < 16; m += 2) {
        const int a = SLOT2(base3 + m);
        const float2 vr = *(const float2*)&xr[a];
        const float2 vi = *(const float2*)&xi[a];
        zr[m] = vr.x; zr[m + 1] = vr.y;
        zi[m] = vi.x; zi[m + 1] = vi.y;
    }
    fft16<INV>(zr, zi);
    if (WB3) {
        __syncthreads();
        const int ob = (tid >> 4) + (tid & 15) * 16;
        #pragma unroll
        for (int j2 = 0; j2 < 16; ++j2) {
            const int a = SLOT2(ob + j2 * 256);
            xr[a] = zr[j2]; xi[a] = zi[j2];
        }
        __syncthreads();
    }
}

// store (retrieve-clone structure): 2048 blocks, 2 pairs each, straight-line.
// Z = FFT(k + i*v) via direct global column loads; A[f] += Z^2 in registers
// (fold FM = (A[f]-conj(A[-f]))/(4i) happens in retrieve); transpose-through-
// LDS epilogue -> contiguous atomics. No pair loop, no prefetch registers.
__global__ __launch_bounds__(256) void store_kernel(
    const float* __restrict__ keys, const float* __restrict__ values,
    float* __restrict__ Are, float* __restrict__ Aim) {
    __shared__ float xr[4352], xi[4352];
    const int tid = (int)threadIdx.x;

    float b1r, b1i, b2r, b2i;
    {
        const float a1 = -6.2831853071795864769f * (float)tid / 4096.f;
        const float a2 = -6.2831853071795864769f * (float)(tid & 15) / 256.f;
        sincosf(a1, &b1i, &b1r);
        sincosf(a2, &b2i, &b2r);
    }

    float aAr[16], aAi[16];
    float zr[16], zi[16];
    const int pair0 = (int)blockIdx.x * 2;

    // ---- pair 0
    {
        const float* kp = keys + (size_t)pair0 * DD;
        const float* vp = values + (size_t)pair0 * DD;
        #pragma unroll
        for (int n = 0; n < 16; ++n) {       // stride-256 coalesced columns
            zr[n] = kp[n * 256 + tid];
            zi[n] = vp[n * 256 + tid];
        }
    }
    fft4096z<0, 0>(xr, xi, zr, zi, b1r, b1i, b2r, b2i, tid);
    #pragma unroll
    for (int j2 = 0; j2 < 16; ++j2) {        // A = Z^2 (register f-slots)
        aAr[j2] = zr[j2] * zr[j2] - zi[j2] * zi[j2];
        aAi[j2] = 2.f * zr[j2] * zi[j2];
    }
    __syncthreads();                         // pass-3 reads retired

    // ---- pair 1
    {
        const float* kp = keys + (size_t)(pair0 + 1) * DD;
        const float* vp = values + (size_t)(pair0 + 1) * DD;
        #pragma unroll
        for (int n = 0; n < 16; ++n) {
            zr[n] = kp[n * 256 + tid];
            zi[n] = vp[n * 256 + tid];
        }
    }
    fft4096z<0, 0>(xr, xi, zr, zi, b1r, b1i, b2r, b2i, tid);
    #pragma unroll
    for (int j2 = 0; j2 < 16; ++j2) {
        aAr[j2] += zr[j2] * zr[j2] - zi[j2] * zi[j2];
        aAi[j2] += 2.f * zr[j2] * zi[j2];
    }
    __syncthreads();

    // epilogue: transpose aA (ob-layout) through LDS -> contiguous atomics
    const int ob = (tid >> 4) + (tid & 15) * 16;
    #pragma unroll
    for (int j2 = 0; j2 < 16; ++j2) {
        const int a = SLOT2(ob + j2 * 256);
        xr[a] = aAr[j2]; xi[a] = aAi[j2];
    }
    __syncthreads();
    #pragma unroll
    for (int r = 0; r < 16; ++r) {
        const int f = tid + 256 * r;
        const int a = SLOT2(f);
        atomicAdd(&Are[f], xr[a]);
        atomicAdd(&Aim[f], xi[a]);
    }
}

// retrieve: Z = FFT(q0 + i*q1); FM[f] = (A[f]-conj(A[-f]))/(4i);
// W[f] = FM[f] * Z[(-f) mod N]; IFFT(W) = row0 + i*row1.  (r12 exact)
__global__ __launch_bounds__(256) void retrieve_kernel(
    const float* __restrict__ queries, const float* __restrict__ Are,
    const float* __restrict__ Aim, float* __restrict__ out) {
    __shared__ float xr[4352], xi[4352];
    const int tid = (int)threadIdx.x;

    float b1r, b1i, b2r, b2i;
    {
        const float a1 = -6.2831853071795864769f * (float)tid / 4096.f;
        const float a2 = -6.2831853071795864769f * (float)(tid & 15) / 256.f;
        sincosf(a1, &b1i, &b1r);
        sincosf(a2, &b2i, &b2r);
    }

    const int q0 = (int)blockIdx.x * 2, q1 = q0 + 1;
    const float* r0 = queries + (size_t)q0 * DD;
    const float* r1 = queries + (size_t)q1 * DD;
    float zr[16], zi[16];
    #pragma unroll
    for (int n = 0; n < 16; ++n) {           // stride-256 coalesced column loads
        zr[n] = r0[n * 256 + tid];
        zi[n] = r1[n * 256 + tid];
    }
    fft4096z<0, 1>(xr, xi, zr, zi, b1r, b1i, b2r, b2i, tid);

    // W build: Z mirrors + A-fold into regs, sync, overwrite in place
    float zmr[16], zmi[16], fmr[16], fmi[16];
    #pragma unroll
    for (int r = 0; r < 16; ++r) {
        const int f = tid + 256 * r;
        const int fn = (DD - f) & (DD - 1);
        zmr[r] = xr[SLOT2(fn)]; zmi[r] = xi[SLOT2(fn)];
        const float pr = Are[f],  pi_ = Aim[f];
        const float qr = Are[fn], qi_ = Aim[fn];
        fmr[r] = 0.25f * (pi_ + qi_);        // FM = (A[f]-conj(A[-f]))/(4i)
        fmi[r] = -0.25f * (pr - qr);
    }
    __syncthreads();
    #pragma unroll
    for (int r = 0; r < 16; ++r) {
        const int f = tid + 256 * r;
        const int a = SLOT2(f);
        xr[a] = fmr[r] * zmr[r] - fmi[r] * zmi[r];
        xi[a] = fmr[r] * zmi[r] + fmi[r] * zmr[r];
    }
    __syncthreads();
    #pragma unroll
    for (int n = 0; n < 16; ++n) {
        const int a = SLOT2(n * 256 + tid);
        zr[n] = xr[a]; zi[n] = xi[a];
    }
    fft4096z<1, 1>(xr, xi, zr, zi, b1r, -b1i, b2r, -b2i, tid);

    const float sc = 1.f / 4096.f;
    float* o0 = out + (size_t)q0 * DD;
    float* o1 = out + (size_t)q1 * DD;
    #pragma unroll
    for (int q = 0; q < 4; ++q) {
        const int j = (tid + 256 * q) * 4;
        const int a = SLOT2(j);
        const float2 r01 = *(const float2*)&xr[a];
        const float2 r23 = *(const float2*)&xr[a + 2];
        const float2 i01 = *(const float2*)&xi[a];
        const float2 i23 = *(const float2*)&xi[a + 2];
        float4 v0, v1;
        v0.x = r01.x * sc; v0.y = r01.y * sc; v0.z = r23.x * sc; v0.w = r23.y * sc;
        v1.x = i01.x * sc; v1.y = i01.y * sc; v1.z = i23.x * sc; v1.w = i23.y * sc;
        ((float4*)o0)[tid + 256 * q] = v0;
        ((float4*)o1)[tid + 256 * q] = v1;
    }
}

extern "C" void kernel_launch(void* const* d_in, const int* in_sizes, int n_in,
                              void* d_out, int out_size, void* d_ws, size_t ws_size,
                              hipStream_t stream) {
    const float* keys    = (const float*)d_in[0];
    const float* values  = (const float*)d_in[1];
    const float* queries = (const float*)d_in[2];
    float* out = (float*)d_out;
    char* ws = (char*)d_ws;

    float* Are = (float*)ws;               // 16KB
    float* Aim = (float*)(ws + 16384);     // 16KB

    hipMemsetAsync(Are, 0, 2 * DD * sizeof(float), stream);

    store_kernel<<<NPAIR / 2, 256, 0, stream>>>(keys, values, Are, Aim);
    retrieve_kernel<<<NQUERY / 2, 256, 0, stream>>>(queries, Are, Aim, out);
}

// Round 18
// 78.303 us; speedup vs baseline: 1.4146x; 1.4146x over previous
//
#include <hip/hip_runtime.h>
#include <stdint.h>

#define DD 4096
#define NPAIR 4096
#define NQUERY 4096
#define PPB 8

// padded LDS slot: +2 floats per 32-float block; keeps float2 alignment,
// <=2-way conflicts on all pass access patterns (r12-verified: conflicts==0).
#define SLOT2(i) ((i) + ((((i) >> 5)) << 1))

// raw barrier: writer-side lgkm drain + s_barrier + compiler fence. Avoids
// __syncthreads()'s vmcnt(0) drain so in-flight global loads survive.
#define LBAR() do { asm volatile("s_waitcnt lgkmcnt(0)" ::: "memory");        \
                    __builtin_amdgcn_s_barrier();                             \
                    asm volatile("" ::: "memory"); } while (0)

// in-register 16-point DFT: z[n] -> z[k], natural order both sides.
template <int INV>
static __device__ __forceinline__ void fft16(float* zr, float* zi) {
    const float K1 = 0.92387953251128674f;   // cos(pi/8)
    const float S1 = 0.38268343236508978f;   // sin(pi/8)
    const float C2 = 0.70710678118654752f;
    float gr[16], gi[16];                    // g[k1*4 + n2]
    #pragma unroll
    for (int n2 = 0; n2 < 4; ++n2) {
        const float x0r = zr[n2],      x0i = zi[n2];
        const float x1r = zr[4 + n2],  x1i = zi[4 + n2];
        const float x2r = zr[8 + n2],  x2i = zi[8 + n2];
        const float x3r = zr[12 + n2], x3i = zi[12 + n2];
        const float s02r = x0r + x2r, s02i = x0i + x2i;
        const float d02r = x0r - x2r, d02i = x0i - x2i;
        const float s13r = x1r + x3r, s13i = x1i + x3i;
        const float d13r = x1r - x3r, d13i = x1i - x3i;
        gr[0 * 4 + n2] = s02r + s13r; gi[0 * 4 + n2] = s02i + s13i;
        gr[2 * 4 + n2] = s02r - s13r; gi[2 * 4 + n2] = s02i - s13i;
        if (!INV) {
            gr[1 * 4 + n2] = d02r + d13i; gi[1 * 4 + n2] = d02i - d13r;
            gr[3 * 4 + n2] = d02r - d13i; gi[3 * 4 + n2] = d02i + d13r;
        } else {
            gr[1 * 4 + n2] = d02r - d13i; gi[1 * 4 + n2] = d02i + d13r;
            gr[3 * 4 + n2] = d02r + d13i; gi[3 * 4 + n2] = d02i - d13r;
        }
    }
#define TW16(K, N, WR, WI) do {                                              \
        const float wr_ = (WR), wi_ = INV ? -(WI) : (WI);                    \
        const float xr_ = gr[(K) * 4 + (N)], xi_ = gi[(K) * 4 + (N)];        \
        gr[(K) * 4 + (N)] = xr_ * wr_ - xi_ * wi_;                           \
        gi[(K) * 4 + (N)] = xr_ * wi_ + xi_ * wr_; } while (0)
    TW16(1, 1, K1, -S1);  TW16(1, 2, C2, -C2);   TW16(1, 3, S1, -K1);
    TW16(2, 1, C2, -C2);  TW16(2, 2, 0.f, -1.f); TW16(2, 3, -C2, -C2);
    TW16(3, 1, S1, -K1);  TW16(3, 2, -C2, -C2);  TW16(3, 3, -K1, S1);
#undef TW16
    #pragma unroll
    for (int k1 = 0; k1 < 4; ++k1) {
        const float x0r = gr[k1 * 4 + 0], x0i = gi[k1 * 4 + 0];
        const float x1r = gr[k1 * 4 + 1], x1i = gi[k1 * 4 + 1];
        const float x2r = gr[k1 * 4 + 2], x2i = gi[k1 * 4 + 2];
        const float x3r = gr[k1 * 4 + 3], x3i = gi[k1 * 4 + 3];
        const float s02r = x0r + x2r, s02i = x0i + x2i;
        const float d02r = x0r - x2r, d02i = x0i - x2i;
        const float s13r = x1r + x3r, s13i = x1i + x3i;
        const float d13r = x1r - x3r, d13i = x1i - x3i;
        zr[k1]      = s02r + s13r; zi[k1]      = s02i + s13i;
        zr[k1 + 8]  = s02r - s13r; zi[k1 + 8]  = s02i - s13i;
        if (!INV) {
            zr[k1 + 4]  = d02r + d13i; zi[k1 + 4]  = d02i - d13r;
            zr[k1 + 12] = d02r - d13i; zi[k1 + 12] = d02i + d13r;
        } else {
            zr[k1 + 4]  = d02r - d13i; zi[k1 + 4]  = d02i + d13r;
            zr[k1 + 12] = d02r + d13i; zi[k1 + 12] = d02i - d13r;
        }
    }
}

// z[k] *= base^k for k=1..15 (chained powers, 2 live regs, no LDS)
static __device__ __forceinline__ void twiddle_chain(float* zr, float* zi,
                                                     float br, float bi) {
    float cr = br, ci = bi;
    #pragma unroll
    for (int k = 1; k < 16; ++k) {
        const float xr = zr[k], xi = zi[k];
        zr[k] = xr * cr - xi * ci;
        zi[k] = xr * ci + xi * cr;
        if (k < 15) {
            const float nr = cr * br - ci * bi;
            const float ni = cr * bi + ci * br;
            cr = nr; ci = ni;
        }
    }
}

// ---- sync-barrier FFT (retrieve path; r12 exact) ----
template <int INV, int WB3>
static __device__ void fft4096z(float* xr, float* xi, float* zr, float* zi,
                                float b1r, float b1i, float b2r, float b2i,
                                int tid) {
    fft16<INV>(zr, zi);
    twiddle_chain(zr, zi, b1r, b1i);
    #pragma unroll
    for (int k = 0; k < 16; ++k) {
        const int a = SLOT2(k * 256 + tid);
        xr[a] = zr[k]; xi[a] = zi[k];
    }
    __syncthreads();
    const int base2 = (tid >> 4) * 256 + (tid & 15);
    #pragma unroll
    for (int m = 0; m < 16; ++m) {
        const int a = SLOT2(base2 + m * 16);
        zr[m] = xr[a]; zi[m] = xi[a];
    }
    fft16<INV>(zr, zi);
    twiddle_chain(zr, zi, b2r, b2i);
    #pragma unroll
    for (int j = 0; j < 16; ++j) {
        const int a = SLOT2(base2 + j * 16);
        xr[a] = zr[j]; xi[a] = zi[j];
    }
    __syncthreads();
    const int base3 = (tid >> 4) * 256 + (tid & 15) * 16;
    #pragma unroll
    for (int m = 0; m < 16; m += 2) {
        const int a = SLOT2(base3 + m);
        const float2 vr = *(const float2*)&xr[a];
        const float2 vi = *(const float2*)&xi[a];
        zr[m] = vr.x; zr[m + 1] = vr.y;
        zi[m] = vi.x; zi[m + 1] = vi.y;
    }
    fft16<INV>(zr, zi);
    if (WB3) {
        __syncthreads();
        const int ob = (tid >> 4) + (tid & 15) * 16;
        #pragma unroll
        for (int j2 = 0; j2 < 16; ++j2) {
            const int a = SLOT2(ob + j2 * 256);
            xr[a] = zr[j2]; xi[a] = zi[j2];
        }
        __syncthreads();
    }
}

// ---- raw-barrier FFT (store path; r12 exact): result stays in regs with
// f = ob + j2*256, ob=(tid>>4)+(tid&15)*16. No trailing barrier.
template <int INV>
static __device__ void fft4096s(float* xr, float* xi, float* zr, float* zi,
                                float b1r, float b1i, float b2r, float b2i,
                                int tid) {
    fft16<INV>(zr, zi);
    twiddle_chain(zr, zi, b1r, b1i);
    #pragma unroll
    for (int k = 0; k < 16; ++k) {
        const int a = SLOT2(k * 256 + tid);
        xr[a] = zr[k]; xi[a] = zi[k];
    }
    LBAR();
    const int base2 = (tid >> 4) * 256 + (tid & 15);
    #pragma unroll
    for (int m = 0; m < 16; ++m) {
        const int a = SLOT2(base2 + m * 16);
        zr[m] = xr[a]; zi[m] = xi[a];
    }
    fft16<INV>(zr, zi);
    twiddle_chain(zr, zi, b2r, b2i);
    #pragma unroll
    for (int j = 0; j < 16; ++j) {
        const int a = SLOT2(base2 + j * 16);
        xr[a] = zr[j]; xi[a] = zi[j];
    }
    LBAR();
    const int base3 = (tid >> 4) * 256 + (tid & 15) * 16;
    #pragma unroll
    for (int m = 0; m < 16; m += 2) {
        const int a = SLOT2(base3 + m);
        const float2 vr = *(const float2*)&xr[a];
        const float2 vi = *(const float2*)&xi[a];
        zr[m] = vr.x; zr[m + 1] = vr.y;
        zi[m] = vi.x; zi[m + 1] = vi.y;
    }
    fft16<INV>(zr, zi);
}

// store: Z = FFT(k + i*v); A[f] += Z^2 in registers (fold to FM in retrieve).
// r12 body exactly; PPB=8 (512 blocks = observed ~2 blk/CU residency) halves
// global atomics; per-block rotation of the atomic loop de-convoys
// same-address contention across concurrent blocks.
__global__ __launch_bounds__(256) void store_kernel(
    const float* __restrict__ keys, const float* __restrict__ values,
    float* __restrict__ Are, float* __restrict__ Aim) {
    __shared__ float xr[4352], xi[4352];
    const int tid = (int)threadIdx.x;

    float b1r, b1i, b2r, b2i;
    {
        const float a1 = -6.2831853071795864769f * (float)tid / 4096.f;
        const float a2 = -6.2831853071795864769f * (float)(tid & 15) / 256.f;
        sincosf(a1, &b1i, &b1r);
        sincosf(a2, &b2i, &b2r);
    }

    float aAr[16], aAi[16];
    #pragma unroll
    for (int r = 0; r < 16; ++r) { aAr[r] = 0.f; aAi[r] = 0.f; }

    const int pair0 = (int)blockIdx.x * PPB;
    float4 ka[4], va[4];
    {
        const float* kp = keys + (size_t)pair0 * DD;
        const float* vp = values + (size_t)pair0 * DD;
        #pragma unroll
        for (int q = 0; q < 4; ++q) {
            ka[q] = ((const float4*)kp)[tid + 256 * q];
            va[q] = ((const float4*)vp)[tid + 256 * q];
        }
    }

    // unroll 1: full unroll inflates prefetch liveness past 128 VGPR (r8).
    #pragma unroll 1
    for (int p = 0; p < PPB; ++p) {
        LBAR();   // prev iteration's pass-3 reads retired
        #pragma unroll
        for (int q = 0; q < 4; ++q) {
            const int j = (tid + 256 * q) * 4;
            const int a = SLOT2(j);            // pad constant over j..j+3
            *(float2*)&xr[a]     = make_float2(ka[q].x, ka[q].y);
            *(float2*)&xr[a + 2] = make_float2(ka[q].z, ka[q].w);
            *(float2*)&xi[a]     = make_float2(va[q].x, va[q].y);
            *(float2*)&xi[a + 2] = make_float2(va[q].z, va[q].w);
        }
        if (p + 1 < PPB) {                     // prefetch: in flight across FFT
            const float* kp = keys + (size_t)(pair0 + p + 1) * DD;
            const float* vp = values + (size_t)(pair0 + p + 1) * DD;
            #pragma unroll
            for (int q = 0; q < 4; ++q) {
                ka[q] = ((const float4*)kp)[tid + 256 * q];
                va[q] = ((const float4*)vp)[tid + 256 * q];
            }
        }
        LBAR();   // scatter visible
        float zr[16], zi[16];
        #pragma unroll
        for (int n = 0; n < 16; ++n) {
            const int a = SLOT2(n * 256 + tid);
            zr[n] = xr[a]; zi[n] = xi[a];
        }
        fft4096s<0>(xr, xi, zr, zi, b1r, b1i, b2r, b2i, tid);
        #pragma unroll
        for (int j2 = 0; j2 < 16; ++j2) {      // A += Z^2 (register f-slots)
            aAr[j2] += zr[j2] * zr[j2] - zi[j2] * zi[j2];
            aAi[j2] += 2.f * zr[j2] * zi[j2];
        }
    }
    // epilogue: transpose aA (ob-layout) through LDS -> contiguous atomics,
    // start index rotated per block to avoid same-address convoying.
    LBAR();
    const int ob = (tid >> 4) + (tid & 15) * 16;
    #pragma unroll
    for (int j2 = 0; j2 < 16; ++j2) {
        const int a = SLOT2(ob + j2 * 256);
        xr[a] = aAr[j2]; xi[a] = aAi[j2];
    }
    LBAR();
    const int rot = (int)blockIdx.x & 15;
    #pragma unroll
    for (int r = 0; r < 16; ++r) {
        const int rr = (r + rot) & 15;
        const int f = tid + 256 * rr;
        const int a = SLOT2(f);
        atomicAdd(&Are[f], xr[a]);
        atomicAdd(&Aim[f], xi[a]);
    }
}

// retrieve: Z = FFT(q0 + i*q1); FM[f] = (A[f]-conj(A[-f]))/(4i);
// W[f] = FM[f] * Z[(-f) mod N]; IFFT(W) = row0 + i*row1.  (r12 exact)
__global__ __launch_bounds__(256) void retrieve_kernel(
    const float* __restrict__ queries, const float* __restrict__ Are,
    const float* __restrict__ Aim, float* __restrict__ out) {
    __shared__ float xr[4352], xi[4352];
    const int tid = (int)threadIdx.x;

    float b1r, b1i, b2r, b2i;
    {
        const float a1 = -6.2831853071795864769f * (float)tid / 4096.f;
        const float a2 = -6.2831853071795864769f * (float)(tid & 15) / 256.f;
        sincosf(a1, &b1i, &b1r);
        sincosf(a2, &b2i, &b2r);
    }

    const int q0 = (int)blockIdx.x * 2, q1 = q0 + 1;
    const float* r0 = queries + (size_t)q0 * DD;
    const float* r1 = queries + (size_t)q1 * DD;
    float zr[16], zi[16];
    #pragma unroll
    for (int n = 0; n < 16; ++n) {           // stride-256 coalesced column loads
        zr[n] = r0[n * 256 + tid];
        zi[n] = r1[n * 256 + tid];
    }
    fft4096z<0, 1>(xr, xi, zr, zi, b1r, b1i, b2r, b2i, tid);

    // W build: Z mirrors + A-fold into regs, sync, overwrite in place
    float zmr[16], zmi[16], fmr[16], fmi[16];
    #pragma unroll
    for (int r = 0; r < 16; ++r) {
        const int f = tid + 256 * r;
        const int fn = (DD - f) & (DD - 1);
        zmr[r] = xr[SLOT2(fn)]; zmi[r] = xi[SLOT2(fn)];
        const float pr = Are[f],  pi_ = Aim[f];
        const float qr = Are[fn], qi_ = Aim[fn];
        fmr[r] = 0.25f * (pi_ + qi_);        // FM = (A[f]-conj(A[-f]))/(4i)
        fmi[r] = -0.25f * (pr - qr);
    }
    __syncthreads();
    #pragma unroll
    for (int r = 0; r < 16; ++r) {
        const int f = tid + 256 * r;
        const int a = SLOT2(f);
        xr[a] = fmr[r] * zmr[r] - fmi[r] * zmi[r];
        xi[a] = fmr[r] * zmi[r] + fmi[r] * zmr[r];
    }
    __syncthreads();
    #pragma unroll
    for (int n = 0; n < 16; ++n) {
        const int a = SLOT2(n * 256 + tid);
        zr[n] = xr[a]; zi[n] = xi[a];
    }
    fft4096z<1, 1>(xr, xi, zr, zi, b1r, -b1i, b2r, -b2i, tid);

    const float sc = 1.f / 4096.f;
    float* o0 = out + (size_t)q0 * DD;
    float* o1 = out + (size_t)q1 * DD;
    #pragma unroll
    for (int q = 0; q < 4; ++q) {
        const int j = (tid + 256 * q) * 4;
        const int a = SLOT2(j);
        const float2 r01 = *(const float2*)&xr[a];
        const float2 r23 = *(const float2*)&xr[a + 2];
        const float2 i01 = *(const float2*)&xi[a];
        const float2 i23 = *(const float2*)&xi[a + 2];
        float4 v0, v1;
        v0.x = r01.x * sc; v0.y = r01.y * sc; v0.z = r23.x * sc; v0.w = r23.y * sc;
        v1.x = i01.x * sc; v1.y = i01.y * sc; v1.z = i23.x * sc; v1.w = i23.y * sc;
        ((float4*)o0)[tid + 256 * q] = v0;
        ((float4*)o1)[tid + 256 * q] = v1;
    }
}

extern "C" void kernel_launch(void* const* d_in, const int* in_sizes, int n_in,
                              void* d_out, int out_size, void* d_ws, size_t ws_size,
                              hipStream_t stream) {
    const float* keys    = (const float*)d_in[0];
    const float* values  = (const float*)d_in[1];
    const float* queries = (const float*)d_in[2];
    float* out = (float*)d_out;
    char* ws = (char*)d_ws;

    float* Are = (float*)ws;               // 16KB
    float* Aim = (float*)(ws + 16384);     // 16KB

    hipMemsetAsync(Are, 0, 2 * DD * sizeof(float), stream);

    store_kernel<<<NPAIR / PPB, 256, 0, stream>>>(keys, values, Are, Aim);
    retrieve_kernel<<<NQUERY / 2, 256, 0, stream>>>(queries, Are, Aim, out);
}